// Round 4
// baseline (85.404 us; speedup 1.0000x reference)
//
#include <hip/hip_runtime.h>

// S4D SSKernelDiag forward: K[h,l] = 2*Re( sum_n C_eff[h,n] * dA[h,n]^l )
// H=1024, N=32, L=4096, C=1. Output (1,H,L) fp32 = 16 MB.
//
// R4: DS instruction count scales with total thread count (2 b128 reads per
// n per thread, independent of JCOUNT). So: TPB 256->128, JCOUNT 16->32
// (grid stays 1024, one block per h) halves per-CU DS to ~2.6 us. VALU is
// halved via pair-interleaved LDS layout: every float4 holds
// (even_n.re, odd_n.re, even_n.im, odd_n.im) so the even/odd recurrences sit
// in adjacent VGPRs straight off ds_read_b128 -> SLP forms v_pk_fma_f32.
// Accumulators are float2 (even/odd partial sums), combined at store.
// Recurrence (step s = dA^128): c_{j+1} = 2Re(s) c_j - |s|^2 c_{j-1},
// roots inside unit circle -> stable; chain depth 30.

#define HDIM    1024
#define NSTATE  32
#define NPAIR   (NSTATE / 2)    // 16
#define SEQ_L   4096
#define TPB     128
#define JCOUNT  (SEQ_L / TPB)   // 32

__global__ __launch_bounds__(TPB) void sskernel_diag(
    const float* __restrict__ log_dt,      // (H,)
    const float* __restrict__ B_ri,        // (H, N, 2)
    const float* __restrict__ C_ri,        // (1, H, N, 2)
    const float* __restrict__ inv_A_real,  // (H, N)
    const float* __restrict__ A_imag,      // (H, N)
    float* __restrict__ out)               // (1, H, L)
{
    // pair-interleaved tables: [pair][slot] = (even.re, odd.re, even.im, odd.im)
    __shared__ float4 s_loA[NPAIR][16];  // (Ceff*dA^t), t=0..15
    __shared__ float4 s_g[NPAIR][8];     // dA^(16u), u=0..7
    __shared__ float4 s_gs[NPAIR][8];    // dA^(16u) * dA^128
    __shared__ float4 s_rec[NPAIR];      // (recx_e, recx_o, recy_e, recy_o)

    const int h   = blockIdx.x;
    const int tid = threadIdx.x;

    if (tid < 2 * NSTATE) {
        const int n    = tid & (NSTATE - 1);
        const int role = tid >> 5;          // 0: loA+rec, 1: g/gs tables
        const int p    = n >> 1;
        const int q    = n & 1;             // even/odd slot
        const int idx  = h * NSTATE + n;

        const float dt   = expf(log_dt[h]);
        const float Ar   = -expf(inv_A_real[idx]);
        const float Ai   = A_imag[idx];
        const float dtAr = Ar * dt;
        const float dtAi = Ai * dt;

        const float dr = 1.0f - 0.5f * dtAr;
        const float di =       -0.5f * dtAi;
        const float inv_den = 1.0f / (dr * dr + di * di);

        const float nr = 1.0f + 0.5f * dtAr;
        const float ni =        0.5f * dtAi;
        const float dAr = (nr * dr + ni * di) * inv_den;   // |dA| < 1
        const float dAi = (ni * dr - nr * di) * inv_den;

        if (role == 0) {
            // dA^128 via 7 squarings -> recurrence coeffs
            float sr = dAr, si = dAi;
            #pragma unroll
            for (int t = 0; t < 7; ++t) {
                const float tr = sr * sr - si * si;
                si = 2.0f * sr * si;
                sr = tr;
            }
            float* rec = (float*)&s_rec[p];
            rec[q]     = 2.0f * sr;
            rec[2 + q] = -(sr * sr + si * si);

            // C_eff (incl. factor 2): 2*dt*(B*C)*conj(denom)/|denom|^2
            const float br = B_ri[2 * idx], bi = B_ri[2 * idx + 1];
            const float cr = C_ri[2 * idx], ci = C_ri[2 * idx + 1];
            const float bcr = br * cr - bi * ci;
            const float bci = br * ci + bi * cr;
            const float scale = 2.0f * dt * inv_den;
            float pr = (bcr * dr + bci * di) * scale;
            float pi = (bci * dr - bcr * di) * scale;

            #pragma unroll
            for (int t = 0; t < 16; ++t) {
                float* e = (float*)&s_loA[p][t];
                e[q]     = pr;
                e[2 + q] = pi;
                const float tr = pr * dAr - pi * dAi;
                pi = pr * dAi + pi * dAr;
                pr = tr;
            }
        } else {
            // e16 = dA^16 (4 squarings); s = dA^128 = e16^8 (3 squarings)
            float er = dAr, ei = dAi;
            #pragma unroll
            for (int t = 0; t < 4; ++t) {
                const float tr = er * er - ei * ei;
                ei = 2.0f * er * ei;
                er = tr;
            }
            float sr = er, si = ei;
            #pragma unroll
            for (int t = 0; t < 3; ++t) {
                const float tr = sr * sr - si * si;
                si = 2.0f * sr * si;
                sr = tr;
            }
            float qr = 1.0f, qi = 0.0f;
            #pragma unroll
            for (int u = 0; u < 8; ++u) {
                float* eg  = (float*)&s_g[p][u];
                float* egs = (float*)&s_gs[p][u];
                eg[q]      = qr;
                eg[2 + q]  = qi;
                egs[q]     = qr * sr - qi * si;
                egs[2 + q] = qr * si + qi * sr;
                const float tr = qr * er - qi * ei;
                qi = qr * ei + qi * er;
                qr = tr;
            }
        }
    }
    __syncthreads();

    float2 acc[JCOUNT];
    #pragma unroll
    for (int j = 0; j < JCOUNT; ++j) acc[j] = make_float2(0.0f, 0.0f);

    const int i_lo = tid & 15;
    const int i_hi = tid >> 4;      // 0..7

    #pragma unroll 2
    for (int p = 0; p < NPAIR; ++p) {
        const float4 LA = s_loA[p][i_lo];  // re_e, re_o, im_e, im_o
        const float4 G  = s_g[p][i_hi];
        const float4 GS = s_gs[p][i_hi];
        const float4 RC = s_rec[p];        // rx_e, rx_o, ry_e, ry_o

        // c0 = Re(loA * g), c1 = Re(loA * g*s) — even (.x) / odd (.y) lanes
        float c0x = LA.x * G.x  - LA.z * G.z;
        float c0y = LA.y * G.y  - LA.w * G.w;
        float c1x = LA.x * GS.x - LA.z * GS.z;
        float c1y = LA.y * GS.y - LA.w * GS.w;
        acc[0].x += c0x;  acc[0].y += c0y;
        acc[1].x += c1x;  acc[1].y += c1y;

        #pragma unroll
        for (int j = 2; j < JCOUNT; ++j) {
            const float c2x = RC.x * c1x + RC.z * c0x;
            const float c2y = RC.y * c1y + RC.w * c0y;
            acc[j].x += c2x;  acc[j].y += c2y;
            c0x = c1x;  c0y = c1y;
            c1x = c2x;  c1y = c2y;
        }
    }

    float* o = out + (size_t)h * SEQ_L + tid;
    #pragma unroll
    for (int j = 0; j < JCOUNT; ++j) o[j * TPB] = acc[j].x + acc[j].y;
}

extern "C" void kernel_launch(void* const* d_in, const int* in_sizes, int n_in,
                              void* d_out, int out_size, void* d_ws, size_t ws_size,
                              hipStream_t stream) {
    const float* log_dt     = (const float*)d_in[0];
    const float* B_ri       = (const float*)d_in[1];
    const float* C_ri       = (const float*)d_in[2];
    const float* inv_A_real = (const float*)d_in[3];
    const float* A_imag     = (const float*)d_in[4];
    float* out = (float*)d_out;

    sskernel_diag<<<HDIM, TPB, 0, stream>>>(log_dt, B_ri, C_ri,
                                            inv_A_real, A_imag, out);
}

// Round 6
// 79.780 us; speedup vs baseline: 1.0705x; 1.0705x over previous
//
#include <hip/hip_runtime.h>

// S4D SSKernelDiag forward: K[h,l] = 2*Re( sum_n C_eff[h,n] * dA[h,n]^l )
// H=1024, N=32, L=4096, C=1. Output (1,H,L) fp32 = 16 MB.
//
// R6: R5's packed hot loop was correct, but setup raced: writing one element
// of an ext_vector_type(4) lvalue in LDS codegens as a 16B read-modify-write,
// and the even-n (q=0) / odd-n (q=1) threads RMW the same float4 slot
// concurrently -> clobber -> 3.7e22 absmax. Fix: scalar element stores via
// volatile float* (true 4-byte stores, as R4 did). Hot loop unchanged from
// R5: f32x2 arithmetic end-to-end -> v_pk_mul/v_pk_fma/v_pk_add dual-FP32,
// even/odd n interleaved per float4 LDS slot so .xy/.zw swizzles of one
// ds_read_b128 give the packed operands.
// Recurrence (step s = dA^128): c_{j+1} = 2Re(s) c_j - |s|^2 c_{j-1};
// roots inside unit circle -> stable; chain depth 30, absmax ~2e-3.

#define HDIM    1024
#define NSTATE  32
#define NPAIR   (NSTATE / 2)    // 16
#define SEQ_L   4096
#define TPB     128
#define JCOUNT  (SEQ_L / TPB)   // 32

typedef float f32x2 __attribute__((ext_vector_type(2)));
typedef float f32x4 __attribute__((ext_vector_type(4)));

__global__ __launch_bounds__(TPB) void sskernel_diag(
    const float* __restrict__ log_dt,      // (H,)
    const float* __restrict__ B_ri,        // (H, N, 2)
    const float* __restrict__ C_ri,        // (1, H, N, 2)
    const float* __restrict__ inv_A_real,  // (H, N)
    const float* __restrict__ A_imag,      // (H, N)
    float* __restrict__ out)               // (1, H, L)
{
    // pair-interleaved: [pair][slot] = (even.re, odd.re, even.im, odd.im)
    __shared__ f32x4 s_loA[NPAIR][16];  // (Ceff*dA^t), t=0..15
    __shared__ f32x4 s_g[NPAIR][8];     // dA^(16u), u=0..7
    __shared__ f32x4 s_gs[NPAIR][8];    // dA^(16u) * dA^128
    __shared__ f32x4 s_rec[NPAIR];      // (rx_e, rx_o, ry_e, ry_o)

    const int h   = blockIdx.x;
    const int tid = threadIdx.x;

    if (tid < 2 * NSTATE) {
        const int n    = tid & (NSTATE - 1);
        const int role = tid >> 5;          // 0: loA+rec, 1: g/gs tables
        const int p    = n >> 1;
        const int q    = n & 1;             // even/odd slot
        const int idx  = h * NSTATE + n;

        const float dt   = expf(log_dt[h]);
        const float Ar   = -expf(inv_A_real[idx]);
        const float Ai   = A_imag[idx];
        const float dtAr = Ar * dt;
        const float dtAi = Ai * dt;

        const float dr = 1.0f - 0.5f * dtAr;
        const float di =       -0.5f * dtAi;
        const float inv_den = 1.0f / (dr * dr + di * di);

        const float nr = 1.0f + 0.5f * dtAr;
        const float ni =        0.5f * dtAi;
        const float dAr = (nr * dr + ni * di) * inv_den;   // |dA| < 1
        const float dAi = (ni * dr - nr * di) * inv_den;

        if (role == 0) {
            // dA^128 via 7 squarings -> recurrence coeffs
            float sr = dAr, si = dAi;
            #pragma unroll
            for (int t = 0; t < 7; ++t) {
                const float tr = sr * sr - si * si;
                si = 2.0f * sr * si;
                sr = tr;
            }
            volatile float* rec = (volatile float*)&s_rec[p];
            rec[q]     = 2.0f * sr;
            rec[2 + q] = -(sr * sr + si * si);

            // C_eff (incl. factor 2): 2*dt*(B*C)*conj(denom)/|denom|^2
            const float br = B_ri[2 * idx], bi = B_ri[2 * idx + 1];
            const float cr = C_ri[2 * idx], ci = C_ri[2 * idx + 1];
            const float bcr = br * cr - bi * ci;
            const float bci = br * ci + bi * cr;
            const float scale = 2.0f * dt * inv_den;
            float pr = (bcr * dr + bci * di) * scale;
            float pi = (bci * dr - bcr * di) * scale;

            #pragma unroll
            for (int t = 0; t < 16; ++t) {
                volatile float* e = (volatile float*)&s_loA[p][t];
                e[q]     = pr;
                e[2 + q] = pi;
                const float tr = pr * dAr - pi * dAi;
                pi = pr * dAi + pi * dAr;
                pr = tr;
            }
        } else {
            // e16 = dA^16 (4 squarings); s = dA^128 = e16^8 (3 squarings)
            float er = dAr, ei = dAi;
            #pragma unroll
            for (int t = 0; t < 4; ++t) {
                const float tr = er * er - ei * ei;
                ei = 2.0f * er * ei;
                er = tr;
            }
            float sr = er, si = ei;
            #pragma unroll
            for (int t = 0; t < 3; ++t) {
                const float tr = sr * sr - si * si;
                si = 2.0f * sr * si;
                sr = tr;
            }
            float qr = 1.0f, qi = 0.0f;
            #pragma unroll
            for (int u = 0; u < 8; ++u) {
                volatile float* eg  = (volatile float*)&s_g[p][u];
                volatile float* egs = (volatile float*)&s_gs[p][u];
                eg[q]      = qr;
                eg[2 + q]  = qi;
                egs[q]     = qr * sr - qi * si;
                egs[2 + q] = qr * si + qi * sr;
                const float tr = qr * er - qi * ei;
                qi = qr * ei + qi * er;
                qr = tr;
            }
        }
    }
    __syncthreads();

    f32x2 acc[JCOUNT];
    #pragma unroll
    for (int j = 0; j < JCOUNT; ++j) acc[j] = (f32x2)(0.0f);

    const int i_lo = tid & 15;
    const int i_hi = tid >> 4;      // 0..7

    #pragma unroll 2
    for (int p = 0; p < NPAIR; ++p) {
        const f32x4 LA = s_loA[p][i_lo];
        const f32x4 G  = s_g[p][i_hi];
        const f32x4 GS = s_gs[p][i_hi];
        const f32x4 RC = s_rec[p];

        const f32x2 LAre = LA.xy, LAim = LA.zw;
        const f32x2 Rx   = RC.xy, Ry   = RC.zw;

        // packed: c0 = Re(loA*g), c1 = Re(loA*g*s) for (even,odd) lanes
        f32x2 c0 = LAre * G.xy  - LAim * G.zw;
        f32x2 c1 = LAre * GS.xy - LAim * GS.zw;
        acc[0] += c0;
        acc[1] += c1;

        #pragma unroll
        for (int j = 2; j < JCOUNT; ++j) {
            const f32x2 c2 = Rx * c1 + Ry * c0;   // v_pk_mul + v_pk_fma
            acc[j] += c2;                          // v_pk_add
            c0 = c1;
            c1 = c2;
        }
    }

    float* o = out + (size_t)h * SEQ_L + tid;
    #pragma unroll
    for (int j = 0; j < JCOUNT; ++j) o[j * TPB] = acc[j].x + acc[j].y;
}

extern "C" void kernel_launch(void* const* d_in, const int* in_sizes, int n_in,
                              void* d_out, int out_size, void* d_ws, size_t ws_size,
                              hipStream_t stream) {
    const float* log_dt     = (const float*)d_in[0];
    const float* B_ri       = (const float*)d_in[1];
    const float* C_ri       = (const float*)d_in[2];
    const float* inv_A_real = (const float*)d_in[3];
    const float* A_imag     = (const float*)d_in[4];
    float* out = (float*)d_out;

    sskernel_diag<<<HDIM, TPB, 0, stream>>>(log_dt, B_ri, C_ri,
                                            inv_A_real, A_imag, out);
}